// Round 1
// baseline (1448.932 us; speedup 1.0000x reference)
//
#include <hip/hip_runtime.h>
#include <hip/hip_bf16.h>
#include <math.h>

// Problem constants
constexpr int B       = 1024;
constexpr int IN_DIM  = 768;
constexpr int HID     = 1024;
constexpr int CLIP    = 512;
constexpr int NG      = 4;
constexpr int DS      = 64;
constexpr int HD      = 64;
constexpr int DIN     = 2 * HID;            // 2048
constexpr int NH      = DIN / HD;           // 32
constexpr int CONV_DIM = DIN + 2 * NG * DS; // 2560
constexpr int DINP    = 2 * DIN + 2 * NG * DS + NH; // 4640
constexpr float EPS   = 1e-5f;

__device__ __forceinline__ float sigmoidf_(float v) { return 1.f / (1.f + expf(-v)); }

// ---------------- LayerNorm ----------------
__global__ __launch_bounds__(256) void ln_kernel(
    const float* __restrict__ in, const float* __restrict__ w,
    const float* __restrict__ bvec, float* __restrict__ out)
{
    int row = blockIdx.x, t = threadIdx.x;
    __shared__ float rs[4], rss[4], stats[2];
    float v[3];
    float s = 0.f, ss = 0.f;
#pragma unroll
    for (int i = 0; i < 3; i++) {
        v[i] = in[row * IN_DIM + i * 256 + t];
        s += v[i]; ss += v[i] * v[i];
    }
    for (int o = 32; o; o >>= 1) { s += __shfl_down(s, o); ss += __shfl_down(ss, o); }
    if ((t & 63) == 0) { rs[t >> 6] = s; rss[t >> 6] = ss; }
    __syncthreads();
    if (t == 0) {
        float S = rs[0] + rs[1] + rs[2] + rs[3];
        float SS = rss[0] + rss[1] + rss[2] + rss[3];
        float mu = S * (1.f / IN_DIM);
        float var = SS * (1.f / IN_DIM) - mu * mu;
        stats[0] = mu; stats[1] = rsqrtf(var + EPS);
    }
    __syncthreads();
    float mu = stats[0], r = stats[1];
#pragma unroll
    for (int i = 0; i < 3; i++) {
        int c = i * 256 + t;
        out[row * IN_DIM + c] = (v[i] - mu) * r * w[c] + bvec[c];
    }
}

// ---------------- GEMM: C = epi(A @ W^T + bias) ----------------
// EPI 0: raw;  1: C = acc * sigmoid(other);  2: C = acc + other;  3: C = other * sigmoid(acc)
template <int EPI>
__global__ __launch_bounds__(256) void gemm_kernel(
    const float* __restrict__ A, const float* __restrict__ W,
    const float* __restrict__ bias, const float* __restrict__ other,
    float* __restrict__ C, int M, int N, int K)
{
    __shared__ float As[16][64];
    __shared__ float Ws[16][64];
    int t = threadIdx.x;
    int tx = t & 15, ty = t >> 4;
    int bm = blockIdx.y * 64, bn = blockIdx.x * 64;
    int lr = t >> 2;            // 0..63
    int lk = (t & 3) * 4;       // 0,4,8,12
    const float* Aptr = A + (size_t)(bm + lr) * K + lk;
    const float* Wptr = W + (size_t)(bn + lr) * K + lk;
    bool wvalid = (bn + lr) < N;
    float acc[4][4] = {};
    for (int k0 = 0; k0 < K; k0 += 16) {
        float4 av = *(const float4*)(Aptr + k0);
        float4 wv = wvalid ? *(const float4*)(Wptr + k0) : make_float4(0.f, 0.f, 0.f, 0.f);
        __syncthreads();
        As[lk + 0][lr] = av.x; As[lk + 1][lr] = av.y; As[lk + 2][lr] = av.z; As[lk + 3][lr] = av.w;
        Ws[lk + 0][lr] = wv.x; Ws[lk + 1][lr] = wv.y; Ws[lk + 2][lr] = wv.z; Ws[lk + 3][lr] = wv.w;
        __syncthreads();
#pragma unroll
        for (int kk = 0; kk < 16; kk++) {
            float4 a = *(const float4*)&As[kk][ty * 4];
            float4 b = *(const float4*)&Ws[kk][tx * 4];
            acc[0][0] = fmaf(a.x, b.x, acc[0][0]); acc[0][1] = fmaf(a.x, b.y, acc[0][1]);
            acc[0][2] = fmaf(a.x, b.z, acc[0][2]); acc[0][3] = fmaf(a.x, b.w, acc[0][3]);
            acc[1][0] = fmaf(a.y, b.x, acc[1][0]); acc[1][1] = fmaf(a.y, b.y, acc[1][1]);
            acc[1][2] = fmaf(a.y, b.z, acc[1][2]); acc[1][3] = fmaf(a.y, b.w, acc[1][3]);
            acc[2][0] = fmaf(a.z, b.x, acc[2][0]); acc[2][1] = fmaf(a.z, b.y, acc[2][1]);
            acc[2][2] = fmaf(a.z, b.z, acc[2][2]); acc[2][3] = fmaf(a.z, b.w, acc[2][3]);
            acc[3][0] = fmaf(a.w, b.x, acc[3][0]); acc[3][1] = fmaf(a.w, b.y, acc[3][1]);
            acc[3][2] = fmaf(a.w, b.z, acc[3][2]); acc[3][3] = fmaf(a.w, b.w, acc[3][3]);
        }
    }
    int cn = bn + tx * 4;
    if (cn < N) {
        float4 bz = bias ? *(const float4*)(bias + cn) : make_float4(0.f, 0.f, 0.f, 0.f);
#pragma unroll
        for (int i = 0; i < 4; i++) {
            int rm = bm + ty * 4 + i;
            size_t off = (size_t)rm * N + cn;
            float4 r = make_float4(acc[i][0] + bz.x, acc[i][1] + bz.y,
                                   acc[i][2] + bz.z, acc[i][3] + bz.w);
            if (EPI == 1) {
                float4 o = *(const float4*)(other + off);
                r.x *= sigmoidf_(o.x); r.y *= sigmoidf_(o.y);
                r.z *= sigmoidf_(o.z); r.w *= sigmoidf_(o.w);
            } else if (EPI == 2) {
                float4 o = *(const float4*)(other + off);
                r.x += o.x; r.y += o.y; r.z += o.z; r.w += o.w;
            } else if (EPI == 3) {
                float4 o = *(const float4*)(other + off);
                r.x = o.x * sigmoidf_(r.x); r.y = o.y * sigmoidf_(r.y);
                r.z = o.z * sigmoidf_(r.z); r.w = o.w * sigmoidf_(r.w);
            }
            *(float4*)(C + off) = r;
        }
    }
}

// ---------------- Conv shift + depthwise conv + silu ----------------
__global__ __launch_bounds__(256) void conv_kernel(
    const float* __restrict__ conv_state, const float* __restrict__ zxbcdt,
    const float* __restrict__ cw, const float* __restrict__ cb,
    float* __restrict__ newconv, float* __restrict__ xbcp)
{
    int idx = blockIdx.x * 256 + threadIdx.x;     // B*CONV_DIM threads
    int b = idx / CONV_DIM, c = idx - b * CONV_DIM;
    float4 cs = ((const float4*)conv_state)[idx];
    float xin = zxbcdt[(size_t)b * DINP + DIN + c];
    float4 nc = make_float4(cs.y, cs.z, cs.w, xin);
    ((float4*)newconv)[idx] = nc;
    float4 w = ((const float4*)cw)[c];
    float s = nc.x * w.x + nc.y * w.y + nc.z * w.z + nc.w * w.w + cb[c];
    xbcp[idx] = s * sigmoidf_(s);
}

// ---------------- dt / dA ----------------
__global__ __launch_bounds__(256) void dt_kernel(
    const float* __restrict__ zxbcdt, const float* __restrict__ dt_bias,
    const float* __restrict__ A_log, float* __restrict__ dtb, float* __restrict__ dab)
{
    int idx = blockIdx.x * 256 + threadIdx.x;   // B*NH
    int b = idx >> 5, h = idx & 31;
    float raw = zxbcdt[(size_t)b * DINP + DIN + CONV_DIM + h] + dt_bias[h];
    float sp = (raw > 20.f) ? raw : log1pf(expf(raw));
    float A = -expf(A_log[h]);
    dtb[idx] = sp;
    dab[idx] = expf(sp * A);
}

// ---------------- SSM state update + y reduction ----------------
__global__ __launch_bounds__(256) void ssm_kernel(
    const float* __restrict__ ssm_state, const float* __restrict__ xbcp,
    const float* __restrict__ dtb, const float* __restrict__ dab,
    const float* __restrict__ Dp, float* __restrict__ newssm, float* __restrict__ ypre)
{
    int bid = blockIdx.x;           // b*NH + h
    int b = bid >> 5, h = bid & 31, g = h >> 3;
    int t = threadIdx.x;
    __shared__ float xsh[64];
    __shared__ float4 Bsh[16], Csh[16];
    __shared__ float sc[3];
    if (t < 64) xsh[t] = xbcp[(size_t)b * CONV_DIM + h * 64 + t];
    else if (t < 80)  Bsh[t - 64] = ((const float4*)(xbcp + (size_t)b * CONV_DIM + DIN + g * 64))[t - 64];
    else if (t < 96)  Csh[t - 80] = ((const float4*)(xbcp + (size_t)b * CONV_DIM + DIN + NG * DS + g * 64))[t - 80];
    else if (t == 96) sc[0] = dtb[bid];
    else if (t == 97) sc[1] = dab[bid];
    else if (t == 98) sc[2] = Dp[h];
    __syncthreads();
    float sdt = sc[0], sdA = sc[1], sDp = sc[2];
    const float4* sin4 = (const float4*)ssm_state + (size_t)bid * 1024;
    float4* sout4 = (float4*)newssm + (size_t)bid * 1024;
#pragma unroll
    for (int i = 0; i < 4; i++) {
        int idx = i * 256 + t;
        int p = idx >> 4, n4 = idx & 15;
        float4 s = sin4[idx];
        float4 Bv = Bsh[n4], Cv = Csh[n4];
        float coef = sdt * xsh[p];
        float4 ns;
        ns.x = fmaf(s.x, sdA, coef * Bv.x);
        ns.y = fmaf(s.y, sdA, coef * Bv.y);
        ns.z = fmaf(s.z, sdA, coef * Bv.z);
        ns.w = fmaf(s.w, sdA, coef * Bv.w);
        sout4[idx] = ns;
        float part = ns.x * Cv.x + ns.y * Cv.y + ns.z * Cv.z + ns.w * Cv.w;
        for (int o = 8; o; o >>= 1) part += __shfl_down(part, o);
        if ((t & 15) == 0) ypre[(size_t)b * DIN + h * 64 + p] = part + sDp * xsh[p];
    }
}

// ---------------- y * silu(z) + grouped RMS norm ----------------
__global__ __launch_bounds__(128) void gn_kernel(
    const float* __restrict__ ypre, const float* __restrict__ zxbcdt,
    const float* __restrict__ nw, float* __restrict__ yfin)
{
    int bg = blockIdx.x;            // b*NG + g
    int b = bg >> 2, g = bg & 3;
    int t = threadIdx.x;
    int col = g * 512 + t * 4;
    float4 yv = *(const float4*)(ypre + (size_t)b * DIN + col);
    float4 zv = *(const float4*)(zxbcdt + (size_t)b * DINP + col);
    float4 y2;
    y2.x = yv.x * zv.x * sigmoidf_(zv.x);
    y2.y = yv.y * zv.y * sigmoidf_(zv.y);
    y2.z = yv.z * zv.z * sigmoidf_(zv.z);
    y2.w = yv.w * zv.w * sigmoidf_(zv.w);
    float ss = y2.x * y2.x + y2.y * y2.y + y2.z * y2.z + y2.w * y2.w;
    for (int o = 32; o; o >>= 1) ss += __shfl_down(ss, o);
    __shared__ float red[2]; __shared__ float rfac;
    if ((t & 63) == 0) red[t >> 6] = ss;
    __syncthreads();
    if (t == 0) rfac = rsqrtf((red[0] + red[1]) * (1.f / 512.f) + EPS);
    __syncthreads();
    float r = rfac;
    float4 w4 = *(const float4*)(nw + col);
    float4 o4 = make_float4(y2.x * r * w4.x, y2.y * r * w4.y, y2.z * r * w4.z, y2.w * r * w4.w);
    *(float4*)(yfin + (size_t)b * DIN + col) = o4;
}

extern "C" void kernel_launch(void* const* d_in, const int* in_sizes, int n_in,
                              void* d_out, int out_size, void* d_ws, size_t ws_size,
                              hipStream_t stream)
{
    const float* frame_feat   = (const float*)d_in[0];
    const float* conv_state   = (const float*)d_in[1];
    const float* ssm_state    = (const float*)d_in[2];
    const float* ln_w         = (const float*)d_in[3];
    const float* ln_b         = (const float*)d_in[4];
    const float* w_in_gate    = (const float*)d_in[5];
    const float* b_in_gate    = (const float*)d_in[6];
    const float* w_input_proj = (const float*)d_in[7];
    const float* b_input_proj = (const float*)d_in[8];
    const float* w_in_proj    = (const float*)d_in[9];
    const float* conv_w       = (const float*)d_in[10];
    const float* conv_b       = (const float*)d_in[11];
    const float* A_log        = (const float*)d_in[12];
    const float* Dp           = (const float*)d_in[13];
    const float* dt_bias      = (const float*)d_in[14];
    const float* norm_w       = (const float*)d_in[15];
    const float* w_out_proj   = (const float*)d_in[16];
    const float* w_out_gate   = (const float*)d_in[17];
    const float* b_out_gate   = (const float*)d_in[18];
    const float* w_proj       = (const float*)d_in[19];
    const float* b_proj       = (const float*)d_in[20];

    float* ws = (float*)d_ws;
    float* x      = ws + 0;                 // 1024*768   = 786432
    float* g1     = ws + 786432;            // 1024*1024  = 1048576
    float* gated  = ws + 1835008;           // 1048576
    float* zxbcdt = ws + 2883584;           // 1024*4640  = 4751360
    float* xbcp   = ws + 7634944;           // 1024*2560  = 2621440
    float* dtb    = ws + 10256384;          // 32768
    float* dab    = ws + 10289152;          // 32768
    float* ypre   = ws + 10321920;          // 2097152
    float* yfin   = ws + 12419072;          // 2097152
    float* outpre = ws + 14516224;          // 1048576
    float* outv   = ws + 15564800;          // 1048576

    float* out     = (float*)d_out;
    float* clip    = out;                                   // 1024*512
    float* newconv = out + (size_t)B * CLIP;                // 1024*2560*4
    float* newssm  = newconv + (size_t)B * CONV_DIM * 4;    // 1024*32*64*64

    // 1. LayerNorm
    ln_kernel<<<B, 256, 0, stream>>>(frame_feat, ln_w, ln_b, x);
    // 2. g1 = x@Wg^T + b
    gemm_kernel<0><<<dim3(HID / 64, B / 64), 256, 0, stream>>>(
        x, w_in_gate, b_in_gate, nullptr, g1, B, HID, IN_DIM);
    // 3. gated = (x@Wp^T + b) * sigmoid(g1)
    gemm_kernel<1><<<dim3(HID / 64, B / 64), 256, 0, stream>>>(
        x, w_input_proj, b_input_proj, g1, gated, B, HID, IN_DIM);
    // 4. zxbcdt = gated @ w_in_proj^T
    gemm_kernel<0><<<dim3((DINP + 63) / 64, B / 64), 256, 0, stream>>>(
        gated, w_in_proj, nullptr, nullptr, zxbcdt, B, DINP, HID);
    // 5. conv shift + conv + silu  (writes new_conv output)
    conv_kernel<<<(B * CONV_DIM) / 256, 256, 0, stream>>>(
        conv_state, zxbcdt, conv_w, conv_b, newconv, xbcp);
    // 6. dt / dA
    dt_kernel<<<(B * NH) / 256, 256, 0, stream>>>(zxbcdt, dt_bias, A_log, dtb, dab);
    // 7. SSM update (writes new_ssm output) + y reduction
    ssm_kernel<<<B * NH, 256, 0, stream>>>(ssm_state, xbcp, dtb, dab, Dp, newssm, ypre);
    // 8. y * silu(z) + group RMS norm
    gn_kernel<<<B * NG, 128, 0, stream>>>(ypre, zxbcdt, norm_w, yfin);
    // 9. outpre = yfin @ w_out_proj^T + gated
    gemm_kernel<2><<<dim3(HID / 64, B / 64), 256, 0, stream>>>(
        yfin, w_out_proj, nullptr, gated, outpre, B, HID, DIN);
    // 10. outv = outpre * sigmoid(outpre @ w_out_gate^T + b)
    gemm_kernel<3><<<dim3(HID / 64, B / 64), 256, 0, stream>>>(
        outpre, w_out_gate, b_out_gate, outpre, outv, B, HID, HID);
    // 11. clip = outv @ w_proj^T + b
    gemm_kernel<0><<<dim3(CLIP / 64, B / 64), 256, 0, stream>>>(
        outv, w_proj, b_proj, nullptr, clip, B, CLIP, HID);
}